// Round 5
// baseline (11635.232 us; speedup 1.0000x reference)
//
#include <hip/hip_runtime.h>

#define NN 100000
#define NE 1600000
#define DIN 128
#define DHID 256
#define DOUT 128

typedef unsigned int u32;
typedef unsigned short u16;

__device__ inline u16 f2bf(float f) {
    u32 u = __float_as_uint(f);
    u32 r = u + 0x7FFFu + ((u >> 16) & 1u);   // RTNE
    return (u16)(r >> 16);
}

// ---------------- degree kernels ----------------
__global__ void deg_kernel(const int* __restrict__ dst, float* __restrict__ deg, int nE) {
    int i = blockIdx.x * 256 + threadIdx.x;
    if (i < nE) atomicAdd(&deg[dst[i]], 1.0f);
}

__global__ void invdeg_kernel(float* __restrict__ deg, int n) {
    int i = blockIdx.x * 256 + threadIdx.x;
    if (i < n) { float d = deg[i]; deg[i] = d > 0.0f ? 1.0f / d : 0.0f; }
}

// ---------------- edge scatter-add kernels ----------------
__global__ void scatter_add4(const float4* __restrict__ feat, const int* __restrict__ src,
                             const int* __restrict__ dstI, float* __restrict__ agg,
                             int F4, int total) {
    int idx = blockIdx.x * 256 + threadIdx.x;
    if (idx >= total) return;
    int e = idx / F4, c = idx - e * F4;
    int s = src[e], d = dstI[e];
    float4 v = feat[(size_t)s * F4 + c];
    float* p = agg + ((size_t)d * F4 + c) * 4;
    atomicAdd(p + 0, v.x); atomicAdd(p + 1, v.y);
    atomicAdd(p + 2, v.z); atomicAdd(p + 3, v.w);
}

__global__ void scatter_add_bf16(const u16* __restrict__ feat, int ldf, int colOff,
                                 const int* __restrict__ src, const int* __restrict__ dstI,
                                 float* __restrict__ agg, int F4, int total) {
    int idx = blockIdx.x * 256 + threadIdx.x;
    if (idx >= total) return;
    int e = idx / F4, c = idx - e * F4;
    int s = src[e], d = dstI[e];
    uint2 u = *(const uint2*)(feat + (size_t)s * ldf + colOff + c * 4);
    float* p = agg + ((size_t)d * F4 + c) * 4;
    atomicAdd(p + 0, __uint_as_float(u.x << 16));
    atomicAdd(p + 1, __uint_as_float(u.x & 0xffff0000u));
    atomicAdd(p + 2, __uint_as_float(u.y << 16));
    atomicAdd(p + 3, __uint_as_float(u.y & 0xffff0000u));
}

__global__ void scatter_add4_scaled(const float4* __restrict__ feat, const int* __restrict__ src,
                                    const int* __restrict__ dstI, const float* __restrict__ invdeg,
                                    float* __restrict__ out, int F4, int total) {
    int idx = blockIdx.x * 256 + threadIdx.x;
    if (idx >= total) return;
    int e = idx / F4, c = idx - e * F4;
    int s = src[e], d = dstI[e];
    float4 v = feat[(size_t)s * F4 + c];
    float sc = invdeg[d];
    float* p = out + ((size_t)d * F4 + c) * 4;
    atomicAdd(p + 0, v.x * sc); atomicAdd(p + 1, v.y * sc);
    atomicAdd(p + 2, v.z * sc); atomicAdd(p + 3, v.w * sc);
}

// ---------------- fused dual-GEMM (mixed dtype) ----------------
#define BM 128
#define BN 128
#define BK 32

struct BF16tag {};

template<typename TA> struct Ld4 {};
template<> struct Ld4<float> {
    static __device__ inline float4 go(const void* p, size_t off) {
        return *(const float4*)((const float*)p + off);
    }
};
template<> struct Ld4<BF16tag> {
    static __device__ inline float4 go(const void* p, size_t off) {
        uint2 u = *(const uint2*)((const u16*)p + off);
        float4 v;
        v.x = __uint_as_float(u.x << 16);
        v.y = __uint_as_float(u.x & 0xffff0000u);
        v.z = __uint_as_float(u.y << 16);
        v.w = __uint_as_float(u.y & 0xffff0000u);
        return v;
    }
};

template<typename TC> struct CIO {};
template<> struct CIO<float> {
    static __device__ inline void load(const void* C, size_t off, float* t) {
        const float* p = (const float*)C + off;
        float4 a = *(const float4*)p, b = *(const float4*)(p + 4);
        t[0]=a.x; t[1]=a.y; t[2]=a.z; t[3]=a.w; t[4]=b.x; t[5]=b.y; t[6]=b.z; t[7]=b.w;
    }
    static __device__ inline void store(void* C, size_t off, const float* t) {
        float* p = (float*)C + off;
        *(float4*)p       = make_float4(t[0], t[1], t[2], t[3]);
        *(float4*)(p + 4) = make_float4(t[4], t[5], t[6], t[7]);
    }
};
template<> struct CIO<BF16tag> {
    static __device__ inline void load(const void* C, size_t off, float* t) {
        uint4 u = *(const uint4*)((const u16*)C + off);
        t[0]=__uint_as_float(u.x<<16); t[1]=__uint_as_float(u.x&0xffff0000u);
        t[2]=__uint_as_float(u.y<<16); t[3]=__uint_as_float(u.y&0xffff0000u);
        t[4]=__uint_as_float(u.z<<16); t[5]=__uint_as_float(u.z&0xffff0000u);
        t[6]=__uint_as_float(u.w<<16); t[7]=__uint_as_float(u.w&0xffff0000u);
    }
    static __device__ inline void store(void* C, size_t off, const float* t) {
        uint4 u;
        u.x = (u32)f2bf(t[0]) | ((u32)f2bf(t[1]) << 16);
        u.y = (u32)f2bf(t[2]) | ((u32)f2bf(t[3]) << 16);
        u.z = (u32)f2bf(t[4]) | ((u32)f2bf(t[5]) << 16);
        u.w = (u32)f2bf(t[6]) | ((u32)f2bf(t[7]) << 16);
        *(uint4*)((u16*)C + off) = u;
    }
};

template<typename TA>
__device__ inline void operand_pass(const void* __restrict__ A, int K, int lda,
                                    const float* __restrict__ W, int ldw,
                                    const float* __restrict__ scale,
                                    int brow, int bcol, int n, int tid,
                                    float As[BK][BM + 4], float Ws[BK][BN + 4],
                                    float acc[8][8]) {
    int tx = tid & 15, ty = tid >> 4;
    for (int kt = 0; kt < K; kt += BK) {
#pragma unroll
        for (int it = 0; it < 4; ++it) {
            int l = tid + it * 256;
            int r = l >> 3;
            int kq = (l & 7) << 2;
            int grow = brow + r;
            float4 v = make_float4(0.f, 0.f, 0.f, 0.f);
            if (grow < n) {
                v = Ld4<TA>::go(A, (size_t)grow * lda + kt + kq);
                if (scale) { float sc = scale[grow]; v.x *= sc; v.y *= sc; v.z *= sc; v.w *= sc; }
            }
            As[kq + 0][r] = v.x; As[kq + 1][r] = v.y;
            As[kq + 2][r] = v.z; As[kq + 3][r] = v.w;
        }
#pragma unroll
        for (int it = 0; it < 4; ++it) {
            int l = tid + it * 256;
            int r = l >> 3;
            int kq = (l & 7) << 2;
            float4 v = *(const float4*)(W + (size_t)(bcol + r) * ldw + kt + kq);
            Ws[kq + 0][r] = v.x; Ws[kq + 1][r] = v.y;
            Ws[kq + 2][r] = v.z; Ws[kq + 3][r] = v.w;
        }
        __syncthreads();
#pragma unroll
        for (int kk = 0; kk < BK; ++kk) {
            float a[8], b[8];
            const float4* ap = (const float4*)&As[kk][ty * 8];
            float4 a0 = ap[0], a1 = ap[1];
            a[0]=a0.x; a[1]=a0.y; a[2]=a0.z; a[3]=a0.w; a[4]=a1.x; a[5]=a1.y; a[6]=a1.z; a[7]=a1.w;
            const float4* bp = (const float4*)&Ws[kk][tx * 8];
            float4 b0 = bp[0], b1 = bp[1];
            b[0]=b0.x; b[1]=b0.y; b[2]=b0.z; b[3]=b0.w; b[4]=b1.x; b[5]=b1.y; b[6]=b1.z; b[7]=b1.w;
#pragma unroll
            for (int i = 0; i < 8; ++i)
#pragma unroll
                for (int j = 0; j < 8; ++j)
                    acc[i][j] = fmaf(a[i], b[j], acc[i][j]);
        }
        __syncthreads();
    }
}

template<typename TA1, typename TA2, typename TC>
__global__ __launch_bounds__(256)
void gemm_fused(const void* __restrict__ A1, int K1, int lda1,
                const float* __restrict__ W1, int ldw1,
                const void* __restrict__ A2, int K2, int lda2,
                const float* __restrict__ W2, int ldw2,
                const float* __restrict__ bias, const float* __restrict__ rowScale,
                void* __restrict__ C, int n, int cout, int relu, int accum)
{
    __shared__ float As[BK][BM + 4];
    __shared__ float Ws[BK][BN + 4];
    int tid = threadIdx.x;
    int tx = tid & 15, ty = tid >> 4;
    int brow = blockIdx.x * BM;
    int bcol = blockIdx.y * BN;

    float acc[8][8];
#pragma unroll
    for (int i = 0; i < 8; ++i)
#pragma unroll
        for (int j = 0; j < 8; ++j) acc[i][j] = 0.f;

    if (A1) operand_pass<TA1>(A1, K1, lda1, W1, ldw1, rowScale, brow, bcol, n, tid, As, Ws, acc);
    if (A2) operand_pass<TA2>(A2, K2, lda2, W2, ldw2, nullptr,  brow, bcol, n, tid, As, Ws, acc);

#pragma unroll
    for (int i = 0; i < 8; ++i) {
        int grow = brow + ty * 8 + i;
        if (grow >= n) continue;
        size_t off = (size_t)grow * cout + bcol + tx * 8;
        float tmp[8];
#pragma unroll
        for (int j = 0; j < 8; ++j) tmp[j] = acc[i][j];
        if (bias) {
#pragma unroll
            for (int j = 0; j < 8; ++j) tmp[j] += bias[bcol + tx * 8 + j];
        }
        if (accum) {
            float old[8];
            CIO<TC>::load(C, off, old);
#pragma unroll
            for (int j = 0; j < 8; ++j) tmp[j] += old[j];
        }
        if (relu) {
#pragma unroll
            for (int j = 0; j < 8; ++j) tmp[j] = fmaxf(tmp[j], 0.f);
        }
        CIO<TC>::store(C, off, tmp);
    }
}

extern "C" void kernel_launch(void* const* d_in, const int* in_sizes, int n_in,
                              void* d_out, int out_size, void* d_ws, size_t ws_size,
                              hipStream_t stream) {
    const float* x   = (const float*)d_in[0];
    const int*   ei  = (const int*)d_in[1];
    const float* Wl1 = (const float*)d_in[2];
    const float* bl1 = (const float*)d_in[3];
    const float* Wr1 = (const float*)d_in[4];
    const float* Wl2 = (const float*)d_in[5];
    const float* bl2 = (const float*)d_in[6];
    const float* Wr2 = (const float*)d_in[7];
    const float* Wl3 = (const float*)d_in[8];
    const float* bl3 = (const float*)d_in[9];
    const float* Wr3 = (const float*)d_in[10];
    float* out = (float*)d_out;

    const int* src = ei;            // edge_index[0]
    const int* dst = ei + NE;       // edge_index[1]

    // workspace layout (total 156,057,600 B ~ 148.8 MiB)
    char* ws = (char*)d_ws;
    float* deg = (float*)ws;                               // 400,000 B
    float* agg = (float*)(ws + (512 << 10));               // 51,200,000 B (reused as t)
    u16*   h1  = (u16*)(ws + 52428800);                    // NN x 256 bf16
    u16*   h2  = (u16*)(ws + 104857600);                   // NN x 256 bf16
    float* t   = agg;

    const size_t SZ_NODE = (size_t)NN * sizeof(float);
    const size_t SZ_AGG  = (size_t)NN * 128 * sizeof(float);

    const int F4 = 32;
    const int totE = NE * F4;
    dim3 sgrid((totE + 255) / 256);
    dim3 g2((NN + BM - 1) / BM, DHID / BN);
    dim3 g1((NN + BM - 1) / BM, DOUT / BN);

    // ---- degrees ----
    hipMemsetAsync(deg, 0, SZ_NODE, stream);
    hipLaunchKernelGGL(deg_kernel, dim3((NE + 255) / 256), dim3(256), 0, stream, dst, deg, NE);
    hipLaunchKernelGGL(invdeg_kernel, dim3((NN + 255) / 256), dim3(256), 0, stream, deg, NN);

    // ---- layer 1 ----
    hipMemsetAsync(agg, 0, SZ_AGG, stream);
    hipLaunchKernelGGL(scatter_add4, sgrid, dim3(256), 0, stream,
                       (const float4*)x, src, dst, agg, F4, totE);
    hipLaunchKernelGGL((gemm_fused<float, float, BF16tag>), g2, dim3(256), 0, stream,
                       agg, DIN, DIN, Wl1, DIN,
                       x, DIN, DIN, Wr1, DIN,
                       bl1, deg, h1, NN, DHID, 1, 0);

    // ---- layer 2 (split-K halves of the aggregation) ----
    hipMemsetAsync(agg, 0, SZ_AGG, stream);
    hipLaunchKernelGGL(scatter_add_bf16, sgrid, dim3(256), 0, stream,
                       h1, DHID, 0, src, dst, agg, F4, totE);
    hipLaunchKernelGGL((gemm_fused<float, BF16tag, BF16tag>), g2, dim3(256), 0, stream,
                       agg, 128, 128, Wl2, DHID,
                       h1, DHID, DHID, Wr2, DHID,
                       bl2, deg, h2, NN, DHID, 0, 0);
    hipMemsetAsync(agg, 0, SZ_AGG, stream);
    hipLaunchKernelGGL(scatter_add_bf16, sgrid, dim3(256), 0, stream,
                       h1, DHID, 128, src, dst, agg, F4, totE);
    hipLaunchKernelGGL((gemm_fused<float, BF16tag, BF16tag>), g2, dim3(256), 0, stream,
                       agg, 128, 128, Wl2 + 128, DHID,
                       nullptr, 0, 0, nullptr, 0,
                       nullptr, deg, h2, NN, DHID, 1, 1);

    // ---- layer 3 (transform-first) ----
    hipLaunchKernelGGL((gemm_fused<BF16tag, BF16tag, float>), g1, dim3(256), 0, stream,
                       h2, DHID, DHID, Wl3, DHID,
                       nullptr, 0, 0, nullptr, 0,
                       nullptr, nullptr, t, NN, DOUT, 0, 0);
    hipLaunchKernelGGL((gemm_fused<BF16tag, BF16tag, float>), g1, dim3(256), 0, stream,
                       h2, DHID, DHID, Wr3, DHID,
                       nullptr, 0, 0, nullptr, 0,
                       bl3, nullptr, out, NN, DOUT, 0, 0);
    hipLaunchKernelGGL(scatter_add4_scaled, sgrid, dim3(256), 0, stream,
                       (const float4*)t, src, dst, deg, out, F4, totE);
}

// Round 6
// 1360.140 us; speedup vs baseline: 8.5544x; 8.5544x over previous
//
#include <hip/hip_runtime.h>

#define NN 100000
#define NE 1600000
#define DIN 128
#define DHID 256
#define DOUT 128

typedef unsigned int u32;
typedef unsigned short u16;

__device__ inline u16 f2bf(float f) {
    u32 u = __float_as_uint(f);
    u32 r = u + 0x7FFFu + ((u >> 16) & 1u);   // RTNE
    return (u16)(r >> 16);
}
__device__ inline u32 pack2(float a, float b) {
    return (u32)f2bf(a) | ((u32)f2bf(b) << 16);
}
__device__ inline float bflo(u32 u) { return __uint_as_float(u << 16); }
__device__ inline float bfhi(u32 u) { return __uint_as_float(u & 0xffff0000u); }

// ---------------- CSR build ----------------
__global__ void deg_count(const int* __restrict__ dst, int* __restrict__ deg, int nE) {
    int i = blockIdx.x * 256 + threadIdx.x;
    if (i < nE) atomicAdd(&deg[dst[i]], 1);
}

// rowptr[i] = disjoint range start (order irrelevant); invdeg[i] = 1/deg
__global__ void alloc_rows(const int* __restrict__ deg, int* __restrict__ rowptr,
                           float* __restrict__ invdeg, int* __restrict__ gcount, int n) {
    int i = blockIdx.x * 256 + threadIdx.x;
    if (i < n) {
        int d = deg[i];
        invdeg[i] = d > 0 ? 1.0f / (float)d : 0.0f;
        rowptr[i] = atomicAdd(gcount, d);
    }
}

__global__ void fill_csr(const int* __restrict__ src, const int* __restrict__ dst,
                         const int* __restrict__ rowptr, int* __restrict__ fill,
                         int* __restrict__ csr, int nE) {
    int e = blockIdx.x * 256 + threadIdx.x;
    if (e < nE) {
        int d = dst[e];
        int pos = atomicAdd(&fill[d], 1);
        csr[rowptr[d] + pos] = src[e];
    }
}

// ---------------- pull-aggregation (one wave per node) ----------------
// x fp32 [NN][128] -> agg bf16 [NN][128] (mean)
__global__ __launch_bounds__(256)
void agg_f32_128(const float2* __restrict__ feat, const int* __restrict__ rowptr,
                 const int* __restrict__ deg, const float* __restrict__ invdeg,
                 const int* __restrict__ csr, u32* __restrict__ aggOut) {
    int w = (blockIdx.x * 256 + threadIdx.x) >> 6;
    int lane = threadIdx.x & 63;
    if (w >= NN) return;
    int base = rowptr[w], dg = deg[w];
    float ax = 0.f, ay = 0.f;
    int j = 0;
    for (; j + 1 < dg; j += 2) {
        int s0 = csr[base + j], s1 = csr[base + j + 1];
        float2 v0 = feat[(size_t)s0 * 64 + lane];
        float2 v1 = feat[(size_t)s1 * 64 + lane];
        ax += v0.x + v1.x; ay += v0.y + v1.y;
    }
    if (j < dg) {
        int s0 = csr[base + j];
        float2 v0 = feat[(size_t)s0 * 64 + lane];
        ax += v0.x; ay += v0.y;
    }
    float iv = invdeg[w];
    aggOut[(size_t)w * 64 + lane] = pack2(ax * iv, ay * iv);
}

// h bf16 [NN][256], cols [c2off*2, c2off*2+128) -> agg bf16 [NN][128] (mean)
__global__ __launch_bounds__(256)
void agg_bf16_128of256(const u32* __restrict__ feat, int c2off,
                       const int* __restrict__ rowptr, const int* __restrict__ deg,
                       const float* __restrict__ invdeg, const int* __restrict__ csr,
                       u32* __restrict__ aggOut) {
    int w = (blockIdx.x * 256 + threadIdx.x) >> 6;
    int lane = threadIdx.x & 63;
    if (w >= NN) return;
    int base = rowptr[w], dg = deg[w];
    float ax = 0.f, ay = 0.f;
    int j = 0;
    for (; j + 1 < dg; j += 2) {
        int s0 = csr[base + j], s1 = csr[base + j + 1];
        u32 u0 = feat[(size_t)s0 * 128 + c2off + lane];
        u32 u1 = feat[(size_t)s1 * 128 + c2off + lane];
        ax += bflo(u0) + bflo(u1); ay += bfhi(u0) + bfhi(u1);
    }
    if (j < dg) {
        u32 u0 = feat[(size_t)csr[base + j] * 128 + c2off + lane];
        ax += bflo(u0); ay += bfhi(u0);
    }
    float iv = invdeg[w];
    aggOut[(size_t)w * 64 + lane] = pack2(ax * iv, ay * iv);
}

// h bf16 [NN][256] -> agg bf16 [NN][256] (mean), 4 cols per lane
__global__ __launch_bounds__(256)
void agg_bf16_256(const uint2* __restrict__ feat, const int* __restrict__ rowptr,
                  const int* __restrict__ deg, const float* __restrict__ invdeg,
                  const int* __restrict__ csr, uint2* __restrict__ aggOut) {
    int w = (blockIdx.x * 256 + threadIdx.x) >> 6;
    int lane = threadIdx.x & 63;
    if (w >= NN) return;
    int base = rowptr[w], dg = deg[w];
    float a0 = 0.f, a1 = 0.f, a2 = 0.f, a3 = 0.f;
    int j = 0;
    for (; j + 1 < dg; j += 2) {
        int s0 = csr[base + j], s1 = csr[base + j + 1];
        uint2 u0 = feat[(size_t)s0 * 64 + lane];
        uint2 u1 = feat[(size_t)s1 * 64 + lane];
        a0 += bflo(u0.x) + bflo(u1.x); a1 += bfhi(u0.x) + bfhi(u1.x);
        a2 += bflo(u0.y) + bflo(u1.y); a3 += bfhi(u0.y) + bfhi(u1.y);
    }
    if (j < dg) {
        uint2 u0 = feat[(size_t)csr[base + j] * 64 + lane];
        a0 += bflo(u0.x); a1 += bfhi(u0.x);
        a2 += bflo(u0.y); a3 += bfhi(u0.y);
    }
    float iv = invdeg[w];
    uint2 r; r.x = pack2(a0 * iv, a1 * iv); r.y = pack2(a2 * iv, a3 * iv);
    aggOut[(size_t)w * 64 + lane] = r;
}

// ---------------- fused dual-GEMM (mixed dtype) ----------------
#define BM 128
#define BN 128
#define BK 32

struct BF16tag {};

template<typename TA> struct Ld4 {};
template<> struct Ld4<float> {
    static __device__ inline float4 go(const void* p, size_t off) {
        return *(const float4*)((const float*)p + off);
    }
};
template<> struct Ld4<BF16tag> {
    static __device__ inline float4 go(const void* p, size_t off) {
        uint2 u = *(const uint2*)((const u16*)p + off);
        float4 v;
        v.x = bflo(u.x); v.y = bfhi(u.x); v.z = bflo(u.y); v.w = bfhi(u.y);
        return v;
    }
};

template<typename TC> struct CIO {};
template<> struct CIO<float> {
    static __device__ inline void load(const void* C, size_t off, float* t) {
        const float* p = (const float*)C + off;
        float4 a = *(const float4*)p, b = *(const float4*)(p + 4);
        t[0]=a.x; t[1]=a.y; t[2]=a.z; t[3]=a.w; t[4]=b.x; t[5]=b.y; t[6]=b.z; t[7]=b.w;
    }
    static __device__ inline void store(void* C, size_t off, const float* t) {
        float* p = (float*)C + off;
        *(float4*)p       = make_float4(t[0], t[1], t[2], t[3]);
        *(float4*)(p + 4) = make_float4(t[4], t[5], t[6], t[7]);
    }
};
template<> struct CIO<BF16tag> {
    static __device__ inline void load(const void* C, size_t off, float* t) {
        uint4 u = *(const uint4*)((const u16*)C + off);
        t[0]=bflo(u.x); t[1]=bfhi(u.x); t[2]=bflo(u.y); t[3]=bfhi(u.y);
        t[4]=bflo(u.z); t[5]=bfhi(u.z); t[6]=bflo(u.w); t[7]=bfhi(u.w);
    }
    static __device__ inline void store(void* C, size_t off, const float* t) {
        uint4 u;
        u.x = pack2(t[0], t[1]); u.y = pack2(t[2], t[3]);
        u.z = pack2(t[4], t[5]); u.w = pack2(t[6], t[7]);
        *(uint4*)((u16*)C + off) = u;
    }
};

template<typename TA>
__device__ inline void operand_pass(const void* __restrict__ A, int K, int lda,
                                    const float* __restrict__ W, int ldw,
                                    int brow, int bcol, int n, int tid,
                                    float As[BK][BM + 4], float Ws[BK][BN + 4],
                                    float acc[8][8]) {
    int tx = tid & 15, ty = tid >> 4;
    for (int kt = 0; kt < K; kt += BK) {
#pragma unroll
        for (int it = 0; it < 4; ++it) {
            int l = tid + it * 256;
            int r = l >> 3;
            int kq = (l & 7) << 2;
            int grow = brow + r;
            float4 v = make_float4(0.f, 0.f, 0.f, 0.f);
            if (grow < n) v = Ld4<TA>::go(A, (size_t)grow * lda + kt + kq);
            As[kq + 0][r] = v.x; As[kq + 1][r] = v.y;
            As[kq + 2][r] = v.z; As[kq + 3][r] = v.w;
        }
#pragma unroll
        for (int it = 0; it < 4; ++it) {
            int l = tid + it * 256;
            int r = l >> 3;
            int kq = (l & 7) << 2;
            float4 v = *(const float4*)(W + (size_t)(bcol + r) * ldw + kt + kq);
            Ws[kq + 0][r] = v.x; Ws[kq + 1][r] = v.y;
            Ws[kq + 2][r] = v.z; Ws[kq + 3][r] = v.w;
        }
        __syncthreads();
#pragma unroll
        for (int kk = 0; kk < BK; ++kk) {
            float a[8], b[8];
            const float4* ap = (const float4*)&As[kk][ty * 8];
            float4 a0 = ap[0], a1 = ap[1];
            a[0]=a0.x; a[1]=a0.y; a[2]=a0.z; a[3]=a0.w; a[4]=a1.x; a[5]=a1.y; a[6]=a1.z; a[7]=a1.w;
            const float4* bp = (const float4*)&Ws[kk][tx * 8];
            float4 b0 = bp[0], b1 = bp[1];
            b[0]=b0.x; b[1]=b0.y; b[2]=b0.z; b[3]=b0.w; b[4]=b1.x; b[5]=b1.y; b[6]=b1.z; b[7]=b1.w;
#pragma unroll
            for (int i = 0; i < 8; ++i)
#pragma unroll
                for (int j = 0; j < 8; ++j)
                    acc[i][j] = fmaf(a[i], b[j], acc[i][j]);
        }
        __syncthreads();
    }
}

template<typename TA1, typename TA2, typename TC>
__global__ __launch_bounds__(256)
void gemm_fused(const void* __restrict__ A1, int K1, int lda1,
                const float* __restrict__ W1, int ldw1,
                const void* __restrict__ A2, int K2, int lda2,
                const float* __restrict__ W2, int ldw2,
                const float* __restrict__ bias,
                void* __restrict__ C, int n, int cout, int relu, int accum)
{
    __shared__ float As[BK][BM + 4];
    __shared__ float Ws[BK][BN + 4];
    int tid = threadIdx.x;
    int tx = tid & 15, ty = tid >> 4;
    int brow = blockIdx.x * BM;
    int bcol = blockIdx.y * BN;

    float acc[8][8];
#pragma unroll
    for (int i = 0; i < 8; ++i)
#pragma unroll
        for (int j = 0; j < 8; ++j) acc[i][j] = 0.f;

    if (A1) operand_pass<TA1>(A1, K1, lda1, W1, ldw1, brow, bcol, n, tid, As, Ws, acc);
    if (A2) operand_pass<TA2>(A2, K2, lda2, W2, ldw2, brow, bcol, n, tid, As, Ws, acc);

#pragma unroll
    for (int i = 0; i < 8; ++i) {
        int grow = brow + ty * 8 + i;
        if (grow >= n) continue;
        size_t off = (size_t)grow * cout + bcol + tx * 8;
        float tmp[8];
#pragma unroll
        for (int j = 0; j < 8; ++j) tmp[j] = acc[i][j];
        if (bias) {
#pragma unroll
            for (int j = 0; j < 8; ++j) tmp[j] += bias[bcol + tx * 8 + j];
        }
        if (accum) {
            float old[8];
            CIO<TC>::load(C, off, old);
#pragma unroll
            for (int j = 0; j < 8; ++j) tmp[j] += old[j];
        }
        if (relu) {
#pragma unroll
            for (int j = 0; j < 8; ++j) tmp[j] = fmaxf(tmp[j], 0.f);
        }
        CIO<TC>::store(C, off, tmp);
    }
}

extern "C" void kernel_launch(void* const* d_in, const int* in_sizes, int n_in,
                              void* d_out, int out_size, void* d_ws, size_t ws_size,
                              hipStream_t stream) {
    const float* x   = (const float*)d_in[0];
    const int*   ei  = (const int*)d_in[1];
    const float* Wl1 = (const float*)d_in[2];
    const float* bl1 = (const float*)d_in[3];
    const float* Wr1 = (const float*)d_in[4];
    const float* Wl2 = (const float*)d_in[5];
    const float* bl2 = (const float*)d_in[6];
    const float* Wr2 = (const float*)d_in[7];
    const float* Wl3 = (const float*)d_in[8];
    const float* bl3 = (const float*)d_in[9];
    const float* Wr3 = (const float*)d_in[10];
    float* out = (float*)d_out;

    const int* src = ei;            // edge_index[0]
    const int* dst = ei + NE;       // edge_index[1]

    // ---- workspace layout (total ~136.0 MB, < 156,057,600 proven safe) ----
    char* ws = (char*)d_ws;
    int*   deg    = (int*)  (ws + 0);           // 400,000
    int*   fill   = (int*)  (ws + 400000);      // 400,000
    int*   gcount = (int*)  (ws + 800000);      // 16
    float* invdeg = (float*)(ws + 800016);      // 400,000
    int*   rowptr = (int*)  (ws + 1200016);     // 400,000
    int*   csr    = (int*)  (ws + 1600016);     // 6,400,000  (ends 8,000,016)
    u16*   aggS   = (u16*)  (ws + 8000128);     // 25,600,000 bf16 [NN][128] (ends 33,600,128)
    u16*   h2     = (u16*)  (ws + 33600128);    // 51,200,000 bf16 [NN][256]
    u16*   h1     = (u16*)  (ws + 84800256);    // 51,200,000 bf16 [NN][256] (also agg3) (ends 136,000,256)
    u16*   agg3   = h1;

    dim3 b256(256);
    dim3 gE((NE + 255) / 256);
    dim3 gN((NN + 255) / 256);
    dim3 gW((NN * 64 + 255) / 256);                 // one wave per node
    dim3 g2((NN + BM - 1) / BM, DHID / BN);
    dim3 g1((NN + BM - 1) / BM, DOUT / BN);

    // ---- CSR build ----
    hipMemsetAsync(ws, 0, 800016, stream);          // deg, fill, gcount
    hipLaunchKernelGGL(deg_count, gE, b256, 0, stream, dst, deg, NE);
    hipLaunchKernelGGL(alloc_rows, gN, b256, 0, stream, deg, rowptr, invdeg, gcount, NN);
    hipLaunchKernelGGL(fill_csr, gE, b256, 0, stream, src, dst, rowptr, fill, csr, NE);

    // ---- layer 1: aggS = mean(x) ; h1 = relu(aggS@Wl1^T + x@Wr1^T + bl1) ----
    hipLaunchKernelGGL(agg_f32_128, gW, b256, 0, stream,
                       (const float2*)x, rowptr, deg, invdeg, csr, (u32*)aggS);
    hipLaunchKernelGGL((gemm_fused<BF16tag, float, BF16tag>), g2, b256, 0, stream,
                       aggS, DIN, DIN, Wl1, DIN,
                       x, DIN, DIN, Wr1, DIN,
                       bl1, h1, NN, DHID, 1, 0);

    // ---- layer 2 (two 128-col halves of the aggregation) ----
    hipLaunchKernelGGL(agg_bf16_128of256, gW, b256, 0, stream,
                       (const u32*)h1, 0, rowptr, deg, invdeg, csr, (u32*)aggS);
    hipLaunchKernelGGL((gemm_fused<BF16tag, BF16tag, BF16tag>), g2, b256, 0, stream,
                       aggS, 128, 128, Wl2, DHID,
                       h1, DHID, DHID, Wr2, DHID,
                       bl2, h2, NN, DHID, 0, 0);
    hipLaunchKernelGGL(agg_bf16_128of256, gW, b256, 0, stream,
                       (const u32*)h1, 64, rowptr, deg, invdeg, csr, (u32*)aggS);
    hipLaunchKernelGGL((gemm_fused<BF16tag, BF16tag, BF16tag>), g2, b256, 0, stream,
                       aggS, 128, 128, Wl2 + 128, DHID,
                       nullptr, 0, 0, nullptr, 0,
                       nullptr, h2, NN, DHID, 1, 1);

    // ---- layer 3: agg3 = mean(h2) ; out = agg3@Wl3^T + h2@Wr3^T + bl3 ----
    hipLaunchKernelGGL(agg_bf16_256, gW, b256, 0, stream,
                       (const uint2*)h2, rowptr, deg, invdeg, csr, (uint2*)agg3);
    hipLaunchKernelGGL((gemm_fused<BF16tag, BF16tag, float>), g1, b256, 0, stream,
                       agg3, DHID, DHID, Wl3, DHID,
                       h2, DHID, DHID, Wr3, DHID,
                       bl3, out, NN, DOUT, 0, 0);
}

// Round 7
// 814.815 us; speedup vs baseline: 14.2796x; 1.6693x over previous
//
#include <hip/hip_runtime.h>

#define NN 100000
#define NE 1600000
#define DIN 128
#define DHID 256
#define DOUT 128

typedef unsigned int u32;
typedef unsigned short u16;

typedef __bf16 bf16x8 __attribute__((ext_vector_type(8)));
typedef float  f32x4  __attribute__((ext_vector_type(4)));

__device__ inline u16 f2bf(float f) {
    u32 u = __float_as_uint(f);
    u32 r = u + 0x7FFFu + ((u >> 16) & 1u);   // RTNE
    return (u16)(r >> 16);
}
__device__ inline u32 pack2(float a, float b) {
    return (u32)f2bf(a) | ((u32)f2bf(b) << 16);
}
__device__ inline float bflo(u32 u) { return __uint_as_float(u << 16); }
__device__ inline float bfhi(u32 u) { return __uint_as_float(u & 0xffff0000u); }

// ---------------- CSR build ----------------
__global__ void deg_count(const int* __restrict__ dst, int* __restrict__ deg, int nE) {
    int i = blockIdx.x * 256 + threadIdx.x;
    if (i < nE) atomicAdd(&deg[dst[i]], 1);
}

__global__ void alloc_rows(const int* __restrict__ deg, int* __restrict__ rowptr,
                           float* __restrict__ invdeg, int* __restrict__ gcount, int n) {
    int i = blockIdx.x * 256 + threadIdx.x;
    if (i < n) {
        int d = deg[i];
        invdeg[i] = d > 0 ? 1.0f / (float)d : 0.0f;
        rowptr[i] = atomicAdd(gcount, d);
    }
}

__global__ void fill_csr(const int* __restrict__ src, const int* __restrict__ dst,
                         const int* __restrict__ rowptr, int* __restrict__ fill,
                         int* __restrict__ csr, int nE) {
    int e = blockIdx.x * 256 + threadIdx.x;
    if (e < nE) {
        int d = dst[e];
        int pos = atomicAdd(&fill[d], 1);
        csr[rowptr[d] + pos] = src[e];
    }
}

// ---------------- pull-aggregation (one wave per node) ----------------
__global__ __launch_bounds__(256)
void agg_f32_128(const float2* __restrict__ feat, const int* __restrict__ rowptr,
                 const int* __restrict__ deg, const float* __restrict__ invdeg,
                 const int* __restrict__ csr, u32* __restrict__ aggOut) {
    int w = (blockIdx.x * 256 + threadIdx.x) >> 6;
    int lane = threadIdx.x & 63;
    if (w >= NN) return;
    int base = rowptr[w], dg = deg[w];
    float ax = 0.f, ay = 0.f;
    int j = 0;
    for (; j + 1 < dg; j += 2) {
        int s0 = csr[base + j], s1 = csr[base + j + 1];
        float2 v0 = feat[(size_t)s0 * 64 + lane];
        float2 v1 = feat[(size_t)s1 * 64 + lane];
        ax += v0.x + v1.x; ay += v0.y + v1.y;
    }
    if (j < dg) {
        float2 v0 = feat[(size_t)csr[base + j] * 64 + lane];
        ax += v0.x; ay += v0.y;
    }
    float iv = invdeg[w];
    aggOut[(size_t)w * 64 + lane] = pack2(ax * iv, ay * iv);
}

__global__ __launch_bounds__(256)
void agg_bf16_128of256(const u32* __restrict__ feat, int c2off,
                       const int* __restrict__ rowptr, const int* __restrict__ deg,
                       const float* __restrict__ invdeg, const int* __restrict__ csr,
                       u32* __restrict__ aggOut) {
    int w = (blockIdx.x * 256 + threadIdx.x) >> 6;
    int lane = threadIdx.x & 63;
    if (w >= NN) return;
    int base = rowptr[w], dg = deg[w];
    float ax = 0.f, ay = 0.f;
    int j = 0;
    for (; j + 1 < dg; j += 2) {
        int s0 = csr[base + j], s1 = csr[base + j + 1];
        u32 u0 = feat[(size_t)s0 * 128 + c2off + lane];
        u32 u1 = feat[(size_t)s1 * 128 + c2off + lane];
        ax += bflo(u0) + bflo(u1); ay += bfhi(u0) + bfhi(u1);
    }
    if (j < dg) {
        u32 u0 = feat[(size_t)csr[base + j] * 128 + c2off + lane];
        ax += bflo(u0); ay += bfhi(u0);
    }
    float iv = invdeg[w];
    aggOut[(size_t)w * 64 + lane] = pack2(ax * iv, ay * iv);
}

__global__ __launch_bounds__(256)
void agg_bf16_256(const uint2* __restrict__ feat, const int* __restrict__ rowptr,
                  const int* __restrict__ deg, const float* __restrict__ invdeg,
                  const int* __restrict__ csr, uint2* __restrict__ aggOut) {
    int w = (blockIdx.x * 256 + threadIdx.x) >> 6;
    int lane = threadIdx.x & 63;
    if (w >= NN) return;
    int base = rowptr[w], dg = deg[w];
    float a0 = 0.f, a1 = 0.f, a2 = 0.f, a3 = 0.f;
    int j = 0;
    for (; j + 1 < dg; j += 2) {
        int s0 = csr[base + j], s1 = csr[base + j + 1];
        uint2 u0 = feat[(size_t)s0 * 64 + lane];
        uint2 u1 = feat[(size_t)s1 * 64 + lane];
        a0 += bflo(u0.x) + bflo(u1.x); a1 += bfhi(u0.x) + bfhi(u1.x);
        a2 += bflo(u0.y) + bflo(u1.y); a3 += bfhi(u0.y) + bfhi(u1.y);
    }
    if (j < dg) {
        uint2 u0 = feat[(size_t)csr[base + j] * 64 + lane];
        a0 += bflo(u0.x); a1 += bfhi(u0.x);
        a2 += bflo(u0.y); a3 += bfhi(u0.y);
    }
    float iv = invdeg[w];
    uint2 r; r.x = pack2(a0 * iv, a1 * iv); r.y = pack2(a2 * iv, a3 * iv);
    aggOut[(size_t)w * 64 + lane] = r;
}

// ---------------- MFMA bf16 dual-GEMM ----------------
// C[n][cout] = act( A1@W1^T + A2@W2^T + bias (+ C_old) )
// A row-major [n][K] (bf16 or fp32); W row-major fp32 [cout][ldw] (converted to bf16 in staging).
#define TM 128
#define TN 128
#define TK 32
#define LDSTR 40   // bf16 elems per LDS row: 80 B (16B-aligned, low-conflict)

template<int AF32>
__device__ inline void mfma_pass(const void* __restrict__ A, int K, int lda,
                                 const float* __restrict__ W, int ldw,
                                 int brow, int bcol, int n,
                                 int tid, int lane, int wr, int wc,
                                 u16* As, u16* Ws, f32x4 (&acc)[4][4])
{
    int rsel = lane & 15;
    int krun = (lane >> 4) << 3;      // 0,8,16,24
    for (int kt = 0; kt < K; kt += TK) {
        __syncthreads();              // previous-iter LDS reads done
#pragma unroll
        for (int it = 0; it < 2; ++it) {
            int c = tid + it * 256;   // 0..511
            int r = c >> 2;           // 0..127
            int k8 = (c & 3) << 3;    // 0,8,16,24
            // A chunk (guarded rows -> zeros)
            uint4 av = make_uint4(0u, 0u, 0u, 0u);
            int grow = brow + r;
            if (grow < n) {
                if (AF32) {
                    const float* gp = (const float*)A + (size_t)grow * lda + kt + k8;
                    float4 v0 = *(const float4*)gp;
                    float4 v1 = *(const float4*)(gp + 4);
                    av = make_uint4(pack2(v0.x, v0.y), pack2(v0.z, v0.w),
                                    pack2(v1.x, v1.y), pack2(v1.z, v1.w));
                } else {
                    av = *(const uint4*)((const u16*)A + (size_t)grow * lda + kt + k8);
                }
            }
            *(uint4*)&As[r * LDSTR + k8] = av;
            // W chunk (always full; fp32 -> bf16)
            const float* wp = W + (size_t)(bcol + r) * ldw + kt + k8;
            float4 w0 = *(const float4*)wp;
            float4 w1 = *(const float4*)(wp + 4);
            *(uint4*)&Ws[r * LDSTR + k8] =
                make_uint4(pack2(w0.x, w0.y), pack2(w0.z, w0.w),
                           pack2(w1.x, w1.y), pack2(w1.z, w1.w));
        }
        __syncthreads();
        bf16x8 a[4], b[4];
#pragma unroll
        for (int mb = 0; mb < 4; ++mb)
            a[mb] = *(const bf16x8*)&As[(64 * wr + 16 * mb + rsel) * LDSTR + krun];
#pragma unroll
        for (int nb = 0; nb < 4; ++nb)
            b[nb] = *(const bf16x8*)&Ws[(64 * wc + 16 * nb + rsel) * LDSTR + krun];
#pragma unroll
        for (int mb = 0; mb < 4; ++mb)
#pragma unroll
            for (int nb = 0; nb < 4; ++nb)
                acc[mb][nb] = __builtin_amdgcn_mfma_f32_16x16x32_bf16(
                    a[mb], b[nb], acc[mb][nb], 0, 0, 0);
    }
}

template<int A1F32, int A2F32, int CF32, int RELU, int ACCUM>
__global__ __launch_bounds__(256)
void gemm_mfma(const void* __restrict__ A1, int K1, int lda1,
               const float* __restrict__ W1, int ldw1,
               const void* __restrict__ A2, int K2, int lda2,
               const float* __restrict__ W2, int ldw2,
               const float* __restrict__ bias,
               void* __restrict__ C, int n, int cout)
{
    __shared__ u16 As[TM * LDSTR];
    __shared__ u16 Ws[TN * LDSTR];
    int tid = threadIdx.x;
    int lane = tid & 63, wid = tid >> 6;
    int wr = wid >> 1, wc = wid & 1;
    int brow = blockIdx.x * TM, bcol = blockIdx.y * TN;

    f32x4 acc[4][4];
#pragma unroll
    for (int i = 0; i < 4; ++i)
#pragma unroll
        for (int j = 0; j < 4; ++j) acc[i][j] = (f32x4){0.f, 0.f, 0.f, 0.f};

    mfma_pass<A1F32>(A1, K1, lda1, W1, ldw1, brow, bcol, n, tid, lane, wr, wc, As, Ws, acc);
    if (K2 > 0)
        mfma_pass<A2F32>(A2, K2, lda2, W2, ldw2, brow, bcol, n, tid, lane, wr, wc, As, Ws, acc);

    // epilogue: D col = lane&15, row = 4*(lane>>4)+reg  (m89-verified layout)
    int rsel = lane & 15;
    int rgrp = (lane >> 4) << 2;
    float bv[4];
#pragma unroll
    for (int nb = 0; nb < 4; ++nb)
        bv[nb] = bias ? bias[bcol + 64 * wc + 16 * nb + rsel] : 0.f;

#pragma unroll
    for (int mb = 0; mb < 4; ++mb) {
        int rowb = brow + 64 * wr + 16 * mb + rgrp;
#pragma unroll
        for (int r = 0; r < 4; ++r) {
            int row = rowb + r;
            if (row >= n) continue;
            size_t rof = (size_t)row * cout;
#pragma unroll
            for (int nb = 0; nb < 4; ++nb) {
                int col = bcol + 64 * wc + 16 * nb + rsel;
                float v = acc[mb][nb][r] + bv[nb];
                if (CF32) {
                    float* p = (float*)C + rof + col;
                    if (ACCUM) v += *p;
                    if (RELU) v = fmaxf(v, 0.f);
                    *p = v;
                } else {
                    u16* p = (u16*)C + rof + col;
                    if (ACCUM) v += __uint_as_float(((u32)(*p)) << 16);
                    if (RELU) v = fmaxf(v, 0.f);
                    *p = f2bf(v);
                }
            }
        }
    }
}

extern "C" void kernel_launch(void* const* d_in, const int* in_sizes, int n_in,
                              void* d_out, int out_size, void* d_ws, size_t ws_size,
                              hipStream_t stream) {
    const float* x   = (const float*)d_in[0];
    const int*   ei  = (const int*)d_in[1];
    const float* Wl1 = (const float*)d_in[2];
    const float* bl1 = (const float*)d_in[3];
    const float* Wr1 = (const float*)d_in[4];
    const float* Wl2 = (const float*)d_in[5];
    const float* bl2 = (const float*)d_in[6];
    const float* Wr2 = (const float*)d_in[7];
    const float* Wl3 = (const float*)d_in[8];
    const float* bl3 = (const float*)d_in[9];
    const float* Wr3 = (const float*)d_in[10];
    float* out = (float*)d_out;

    const int* src = ei;            // edge_index[0]
    const int* dst = ei + NE;       // edge_index[1]

    // ---- workspace layout (total ~136.0 MB, < 156,057,600 proven safe) ----
    char* ws = (char*)d_ws;
    int*   deg    = (int*)  (ws + 0);           // 400,000
    int*   fill   = (int*)  (ws + 400000);      // 400,000
    int*   gcount = (int*)  (ws + 800000);      // 16
    float* invdeg = (float*)(ws + 800016);      // 400,000
    int*   rowptr = (int*)  (ws + 1200016);     // 400,000
    int*   csr    = (int*)  (ws + 1600016);     // 6,400,000
    u16*   aggS   = (u16*)  (ws + 8000128);     // 25,600,000 bf16 [NN][128]
    u16*   h2     = (u16*)  (ws + 33600128);    // 51,200,000 bf16 [NN][256]
    u16*   h1     = (u16*)  (ws + 84800256);    // 51,200,000 bf16 [NN][256] (reused as agg3)
    u16*   agg3   = h1;

    dim3 b256(256);
    dim3 gE((NE + 255) / 256);
    dim3 gN((NN + 255) / 256);
    dim3 gW((NN * 64 + 255) / 256);             // one wave per node
    dim3 gg2((NN + TM - 1) / TM, DHID / TN);    // cout=256
    dim3 gg1((NN + TM - 1) / TM, DOUT / TN);    // cout=128

    // ---- CSR build ----
    hipMemsetAsync(ws, 0, 800016, stream);      // deg, fill, gcount
    hipLaunchKernelGGL(deg_count, gE, b256, 0, stream, dst, deg, NE);
    hipLaunchKernelGGL(alloc_rows, gN, b256, 0, stream, deg, rowptr, invdeg, gcount, NN);
    hipLaunchKernelGGL(fill_csr, gE, b256, 0, stream, src, dst, rowptr, fill, csr, NE);

    // ---- layer 1: aggS = mean(x); h1 = relu(aggS@Wl1^T + x@Wr1^T + bl1) ----
    hipLaunchKernelGGL(agg_f32_128, gW, b256, 0, stream,
                       (const float2*)x, rowptr, deg, invdeg, csr, (u32*)aggS);
    hipLaunchKernelGGL((gemm_mfma<0, 1, 0, 1, 0>), gg2, b256, 0, stream,
                       aggS, DIN, DIN, Wl1, DIN,
                       x, DIN, DIN, Wr1, DIN,
                       bl1, h1, NN, DHID);

    // ---- layer 2 (two 128-col halves of the aggregation) ----
    hipLaunchKernelGGL(agg_bf16_128of256, gW, b256, 0, stream,
                       (const u32*)h1, 0, rowptr, deg, invdeg, csr, (u32*)aggS);
    hipLaunchKernelGGL((gemm_mfma<0, 0, 0, 0, 0>), gg2, b256, 0, stream,
                       aggS, 128, 128, Wl2, DHID,
                       h1, DHID, DHID, Wr2, DHID,
                       bl2, h2, NN, DHID);
    hipLaunchKernelGGL(agg_bf16_128of256, gW, b256, 0, stream,
                       (const u32*)h1, 64, rowptr, deg, invdeg, csr, (u32*)aggS);
    hipLaunchKernelGGL((gemm_mfma<0, 0, 0, 1, 1>), gg2, b256, 0, stream,
                       aggS, 128, 128, Wl2 + 128, DHID,
                       nullptr, 0, 0, nullptr, 0,
                       nullptr, h2, NN, DHID);

    // ---- layer 3: agg3 = mean(h2); out = agg3@Wl3^T + h2@Wr3^T + bl3 ----
    hipLaunchKernelGGL(agg_bf16_256, gW, b256, 0, stream,
                       (const uint2*)h2, rowptr, deg, invdeg, csr, (uint2*)agg3);
    hipLaunchKernelGGL((gemm_mfma<0, 0, 1, 0, 0>), gg1, b256, 0, stream,
                       agg3, DHID, DHID, Wl3, DHID,
                       h2, DHID, DHID, Wr3, DHID,
                       bl3, out, NN, DOUT);
}